// Round 13
// baseline (635.978 us; speedup 1.0000x reference)
//
#include <hip/hip_runtime.h>

#define HDIM 1024
#define MMEM 8192
#define TOPK 2048
#define NROWS 8192
#define LNEPS 1e-5f

typedef unsigned short ushort_t;
typedef __bf16 bf16x8 __attribute__((ext_vector_type(8)));
typedef float f32x4 __attribute__((ext_vector_type(4)));
typedef __attribute__((address_space(1))) const void GVoid;
typedef __attribute__((address_space(3))) void LVoid;

// ---------- helpers ----------
__device__ __forceinline__ ushort_t f2bf(float f) {
    union { float f; unsigned u; } c; c.f = f;
    unsigned r = c.u + 0x7fffu + ((c.u >> 16) & 1u);
    return (ushort_t)(r >> 16);
}
__device__ __forceinline__ float bf2f(ushort_t u) {
    union { unsigned u; float f; } c; c.u = ((unsigned)u) << 16; return c.f;
}
__device__ __forceinline__ float blk_red(float v, int op, float* red) {
    #pragma unroll
    for (int o = 32; o; o >>= 1) {
        float u = __shfl_down(v, o);
        v = op ? fmaxf(v, u) : v + u;
    }
    if ((threadIdx.x & 63) == 0) red[threadIdx.x >> 6] = v;
    __syncthreads();
    float r = op ? fmaxf(fmaxf(red[0], red[1]), fmaxf(red[2], red[3]))
                 : (red[0] + red[1]) + (red[2] + red[3]);
    __syncthreads();
    return r;
}

// ---------- top-k with inlined selection-score computation ----------
__global__ __launch_bounds__(256) void topk_rank(const float* __restrict__ sp,
        const float* __restrict__ imp, const float* __restrict__ rec,
        const float* __restrict__ ac, int* __restrict__ idx) {
    __shared__ float s[MMEM];
    __shared__ int pc[256];
    __shared__ float red[4];
    float p0 = sp[0], p1 = sp[1], p2 = sp[2];
    float mx3 = fmaxf(p0, fmaxf(p1, p2));
    float e0 = __expf(p0 - mx3), e1 = __expf(p1 - mx3), e2 = __expf(p2 - mx3);
    float inv3 = 1.f / (e0 + e1 + e2);
    float w0 = e0 * inv3, w1 = e1 * inv3, w2 = e2 * inv3;
    float m = -1e30f;
    for (int i = threadIdx.x; i < MMEM; i += 256) m = fmaxf(m, ac[i]);
    m = blk_red(m, 1, red);
    float rinv = 1.f / m;
    for (int i = threadIdx.x; i < MMEM; i += 256)
        s[i] = w0 * imp[i] + w1 * rec[i] + w2 * (ac[i] * rinv);
    __syncthreads();
    const int li = threadIdx.x & 31;
    const int jc = threadIdx.x >> 5;
    const int i  = blockIdx.x * 32 + li;
    const float si = s[i];
    int cnt = 0;
    const float4* sv = reinterpret_cast<const float4*>(s) + jc * 256;
    #pragma unroll 4
    for (int t = 0; t < 256; ++t) {
        float4 v = sv[t];
        int j0 = jc * 1024 + t * 4;
        cnt += (v.x > si) || (v.x == si && (j0 + 0) < i);
        cnt += (v.y > si) || (v.y == si && (j0 + 1) < i);
        cnt += (v.z > si) || (v.z == si && (j0 + 2) < i);
        cnt += (v.w > si) || (v.w == si && (j0 + 3) < i);
    }
    pc[threadIdx.x] = cnt;
    __syncthreads();
    if (threadIdx.x < 32) {
        int r = 0;
        #pragma unroll
        for (int c = 0; c < 8; ++c) r += pc[c * 32 + threadIdx.x];
        if (r < TOPK) idx[r] = blockIdx.x * 32 + threadIdx.x;
    }
}

__global__ __launch_bounds__(256) void gather_ln(const float* __restrict__ mem_keys,
        const int* __restrict__ idx, const float* __restrict__ g,
        const float* __restrict__ b, ushort_t* __restrict__ out) {
    __shared__ float red[4];
    int src = idx[blockIdx.x] & (MMEM - 1);
    const float* x = mem_keys + (size_t)src * HDIM;
    float4 v = reinterpret_cast<const float4*>(x)[threadIdx.x];
    float s = v.x + v.y + v.z + v.w;
    float ss = v.x*v.x + v.y*v.y + v.z*v.z + v.w*v.w;
    s  = blk_red(s, 0, red);
    ss = blk_red(ss, 0, red);
    float mu = s * (1.f / HDIM);
    float var = ss * (1.f / HDIM) - mu * mu;
    float rstd = rsqrtf(var + LNEPS);
    int c = threadIdx.x * 4;
    ushort4 o;
    o.x = f2bf((v.x - mu) * rstd * g[c+0] + b[c+0]);
    o.y = f2bf((v.y - mu) * rstd * g[c+1] + b[c+1]);
    o.z = f2bf((v.z - mu) * rstd * g[c+2] + b[c+2]);
    o.w = f2bf((v.w - mu) * rstd * g[c+3] + b[c+3]);
    *reinterpret_cast<ushort4*>(out + (size_t)blockIdx.x * HDIM + c) = o;
}

// generic f32 -> bf16 (grid = elems/1024)
__global__ __launch_bounds__(256) void cvt_bf16(const float* __restrict__ in,
                                                ushort_t* __restrict__ out) {
    size_t i = ((size_t)blockIdx.x * 256 + threadIdx.x) * 4;
    float4 v = *reinterpret_cast<const float4*>(in + i);
    ushort4 o = { f2bf(v.x), f2bf(v.y), f2bf(v.z), f2bf(v.w) };
    *reinterpret_cast<ushort4*>(out + i) = o;
}

// merged weight conversion
__global__ __launch_bounds__(256) void cvt_all(const float* __restrict__ in_w,
        const float* __restrict__ gate_w, const float* __restrict__ int_w1,
        const float* __restrict__ int_w2,
        ushort_t* __restrict__ inw_bf, ushort_t* __restrict__ gw3,
        ushort_t* __restrict__ intw2_bf) {
    const int b = blockIdx.x;
    const float* src; ushort_t* dst; int rel;
    if      (b < 3072) { src = in_w;   dst = inw_bf;        rel = b; }
    else if (b < 5120) { src = gate_w; dst = gw3;           rel = b - 3072; }
    else if (b < 9216) { src = int_w1; dst = gw3 + 2097152; rel = b - 5120; }
    else               { src = int_w2; dst = intw2_bf;      rel = b - 9216; }
    size_t i = ((size_t)rel * 256 + threadIdx.x) * 4;
    float4 v = *reinterpret_cast<const float4*>(src + i);
    ushort4 o = { f2bf(v.x), f2bf(v.y), f2bf(v.z), f2bf(v.w) };
    *reinterpret_cast<ushort4*>(dst + i) = o;
}

// two 1024x1024 f32 -> bf16 TRANSPOSED (z selects pair)
__global__ __launch_bounds__(256) void cvt_t2(const float* __restrict__ a,
        const float* __restrict__ b, ushort_t* __restrict__ oa,
        ushort_t* __restrict__ ob) {
    __shared__ ushort_t t[64][65];
    const float* in = blockIdx.z ? b : a;
    ushort_t* out   = blockIdx.z ? ob : oa;
    const int bx = blockIdx.x * 64, by = blockIdx.y * 64;
    const int r = threadIdx.x >> 4, c4 = (threadIdx.x & 15) << 2;
    #pragma unroll
    for (int rr = 0; rr < 64; rr += 16) {
        float4 v = *reinterpret_cast<const float4*>(in + (size_t)(by + r + rr) * 1024 + bx + c4);
        t[r + rr][c4 + 0] = f2bf(v.x);
        t[r + rr][c4 + 1] = f2bf(v.y);
        t[r + rr][c4 + 2] = f2bf(v.z);
        t[r + rr][c4 + 3] = f2bf(v.w);
    }
    __syncthreads();
    #pragma unroll
    for (int rr = 0; rr < 64; rr += 16) {
        const int i = r + rr;
        ushort4 o = { t[c4 + 0][i], t[c4 + 1][i], t[c4 + 2][i], t[c4 + 3][i] };
        *reinterpret_cast<ushort4*>(out + (size_t)(bx + i) * 1024 + by + c4) = o;
    }
}

// merged bias folds
__global__ __launch_bounds__(256) void bias_folds(const float* __restrict__ in_w,
        const float* __restrict__ bq, const float* __restrict__ in_b,
        const float* __restrict__ gate_w, const float* __restrict__ int_w1,
        const float* __restrict__ gate_b, const float* __restrict__ int_b1,
        const float* __restrict__ out_b, float* __restrict__ beff,
        float* __restrict__ beff3) {
    __shared__ float red[4];
    const int b = blockIdx.x;
    const float* wrow; const float* vec;
    if (b < 1024) { wrow = in_w + (size_t)b * 1024; vec = bq; }
    else {
        const int j = b - 1024;
        wrow = (j < 1024 ? gate_w + (size_t)j * 2048
                         : int_w1 + (size_t)(j - 1024) * 2048) + 1024;
        vec = out_b;
    }
    const float4 wv = reinterpret_cast<const float4*>(wrow)[threadIdx.x];
    const float4 bv = reinterpret_cast<const float4*>(vec)[threadIdx.x];
    float s = wv.x*bv.x + wv.y*bv.y + wv.z*bv.z + wv.w*bv.w;
    s = blk_red(s, 0, red);
    if (threadIdx.x == 0) {
        if (b < 1024) beff[b] = s + in_b[b];
        else {
            const int j = b - 1024;
            beff3[j] = s + (j < 1024 ? gate_b[j] : int_b1[j - 1024]);
        }
    }
}

__global__ __launch_bounds__(256) void ln_gelu(ushort_t* h1,
        const float* __restrict__ g, const float* __restrict__ b) {
    __shared__ float red[4];
    ushort_t* p = h1 + (size_t)blockIdx.x * 2048 + threadIdx.x * 8;
    ushort4 a = reinterpret_cast<const ushort4*>(p)[0];
    ushort4 c = reinterpret_cast<const ushort4*>(p)[1];
    float v[8] = { bf2f(a.x), bf2f(a.y), bf2f(a.z), bf2f(a.w),
                   bf2f(c.x), bf2f(c.y), bf2f(c.z), bf2f(c.w) };
    float s = 0.f, ss = 0.f;
    #pragma unroll
    for (int j = 0; j < 8; ++j) { s += v[j]; ss += v[j]*v[j]; }
    s  = blk_red(s, 0, red);
    ss = blk_red(ss, 0, red);
    float mu = s * (1.f / 2048.f);
    float var = ss * (1.f / 2048.f) - mu * mu;
    float rstd = rsqrtf(var + LNEPS);
    int c0 = threadIdx.x * 8;
    ushort_t o[8];
    #pragma unroll
    for (int j = 0; j < 8; ++j) {
        float xn = (v[j] - mu) * rstd * g[c0 + j] + b[c0 + j];
        float ge = 0.5f * xn * (1.f + erff(xn * 0.70710678118654752f));
        o[j] = f2bf(ge);
    }
    ushort4 o1 = { o[0], o[1], o[2], o[3] };
    ushort4 o2 = { o[4], o[5], o[6], o[7] };
    reinterpret_cast<ushort4*>(p)[0] = o1;
    reinterpret_cast<ushort4*>(p)[1] = o2;
}

__global__ __launch_bounds__(256) void final_ln(const float* __restrict__ x,
        const ushort_t* __restrict__ gate, const ushort_t* __restrict__ integ,
        const float* __restrict__ g, const float* __restrict__ b,
        float* __restrict__ out) {
    __shared__ float red[4];
    size_t base = (size_t)blockIdx.x * HDIM + threadIdx.x * 4;
    float4 xv = *reinterpret_cast<const float4*>(x + base);
    ushort4 gv = *reinterpret_cast<const ushort4*>(gate + base);
    ushort4 iv = *reinterpret_cast<const ushort4*>(integ + base);
    float v[4] = { xv.x + bf2f(gv.x)*bf2f(iv.x), xv.y + bf2f(gv.y)*bf2f(iv.y),
                   xv.z + bf2f(gv.z)*bf2f(iv.z), xv.w + bf2f(gv.w)*bf2f(iv.w) };
    float s = v[0]+v[1]+v[2]+v[3];
    float ss = v[0]*v[0]+v[1]*v[1]+v[2]*v[2]+v[3]*v[3];
    s  = blk_red(s, 0, red);
    ss = blk_red(ss, 0, red);
    float mu = s * (1.f / HDIM);
    float var = ss * (1.f / HDIM) - mu * mu;
    float rstd = rsqrtf(var + LNEPS);
    int c = threadIdx.x * 4;
    float4 o;
    o.x = (v[0] - mu) * rstd * g[c+0] + b[c+0];
    o.y = (v[1] - mu) * rstd * g[c+1] + b[c+1];
    o.z = (v[2] - mu) * rstd * g[c+2] + b[c+2];
    o.w = (v[3] - mu) * rstd * g[c+3] + b[c+3];
    *reinterpret_cast<float4*>(out + base) = o;
}

// ---------- fused flash attention (QBLK=64, KCHUNK=128, persistent Q-LDS) ----
// grid (32 row-blocks of 64, 16 z = b*4+h), 256 threads (4 waves).
// Q staged ONCE into Qlds (4 slabs of [64][64]). Per chunk of 128 keys:
// S=Q.Kc^T (K staged per k0) -> exp -> P in swizzled LDS + rowsum
// -> O += P.Vc. Final: O /= rowsum.
__global__ __launch_bounds__(256, 2)
void fattn(const ushort_t* __restrict__ Q, const ushort_t* __restrict__ Kb,
           const ushort_t* __restrict__ Vt, ushort_t* __restrict__ ctx)
{
    __shared__ __align__(16) ushort_t Qlds[16384];   // 4 slabs [64][64] = 32 KB
    __shared__ __align__(16) ushort_t Pb[8192];      // 64 x 128 bf16 (swizzled)
    __shared__ __align__(16) ushort_t Stg[16384];    // K 16KB | V 32KB
    __shared__ float rsum[64];

    const int z1 = blockIdx.y >> 2, z2 = blockIdx.y & 3;
    const int m0 = blockIdx.x * 64;
    const ushort_t* Qp = Q  + (size_t)z1 * 2097152 + z2 * 256;   // ld 1024
    const ushort_t* Kp = Kb + z2 * 256;                           // ld 1024
    const ushort_t* Vp = Vt + (size_t)z2 * 524288;                // ld 2048

    const int tid = threadIdx.x;
    const int w = tid >> 6, l = tid & 63;
    const int srow = l >> 3;
    const int scol = ((l & 7) ^ srow) << 3;
    const int l15 = l & 15, lh = l >> 4;

    if (tid < 64) rsum[tid] = 0.f;

    // ---- stage Q once: 4 slabs of [64 rows][64 cols] ----
    #pragma unroll
    for (int s = 0; s < 4; ++s) {
        #pragma unroll
        for (int i = 0; i < 2; ++i) {
            const int c = i * 4 + w;                   // 0..7 -> rows c*8..c*8+7
            const ushort_t* g = Qp + (size_t)(m0 + c * 8 + srow) * 1024 + s * 64 + scol;
            __builtin_amdgcn_global_load_lds((GVoid*)g,
                (LVoid*)(Qlds + s * 4096 + c * 512), 16, 0, 0);
        }
    }
    __syncthreads();

    f32x4 oacc[4][4] = {};

    for (int ch = 0; ch < 16; ++ch) {
        f32x4 sacc[4][2] = {};
        // ---- S = Q . Kc^T (D = 256) ----
        for (int k0 = 0; k0 < 256; k0 += 64) {
            const int slab = k0 >> 6;
            #pragma unroll
            for (int i = 0; i < 4; ++i) {
                const int c = i * 4 + w;               // K rows 0..127 of chunk
                const ushort_t* g = Kp + (size_t)(ch * 128 + c * 8 + srow) * 1024 + k0 + scol;
                __builtin_amdgcn_global_load_lds((GVoid*)g, (LVoid*)(Stg + c * 512), 16, 0, 0);
            }
            __syncthreads();
            #pragma unroll
            for (int kk = 0; kk < 2; ++kk) {
                bf16x8 af[4], bv[2];
                #pragma unroll
                for (int m = 0; m < 4; ++m) {
                    const int row = m * 16 + l15;
                    const int cb = ((kk * 64) + lh * 16) ^ ((row & 7) << 4);
                    af[m] = *reinterpret_cast<const bf16x8*>(
                        reinterpret_cast<const char*>(Qlds) + slab * 8192 + row * 128 + cb);
                }
                #pragma unroll
                for (int n = 0; n < 2; ++n) {
                    const int row = w * 32 + n * 16 + l15;
                    const int cb = ((kk * 64) + lh * 16) ^ ((row & 7) << 4);
                    bv[n] = *reinterpret_cast<const bf16x8*>(
                        reinterpret_cast<const char*>(Stg) + row * 128 + cb);
                }
                #pragma unroll
                for (int m = 0; m < 4; ++m)
                    #pragma unroll
                    for (int n = 0; n < 2; ++n)
                        sacc[m][n] = __builtin_amdgcn_mfma_f32_16x16x32_bf16(
                            af[m], bv[n], sacc[m][n], 0, 0, 0);
            }
            __syncthreads();
        }
        // ---- exp, P -> LDS (swizzled), rowsum ----
        #pragma unroll
        for (int m = 0; m < 4; ++m) {
            float ps[4] = {0.f, 0.f, 0.f, 0.f};
            #pragma unroll
            for (int n = 0; n < 2; ++n) {
                const int pcol = w * 32 + n * 16 + l15;
                #pragma unroll
                for (int j = 0; j < 4; ++j) {
                    const int prow = m * 16 + lh * 4 + j;
                    float e = __expf(sacc[m][n][j] * 0.0625f);
                    ps[j] += e;
                    const int cb = (pcol * 2) ^ ((prow & 7) << 4);
                    *reinterpret_cast<ushort_t*>(
                        reinterpret_cast<char*>(Pb) + prow * 256 + cb) = f2bf(e);
                }
            }
            #pragma unroll
            for (int j = 0; j < 4; ++j) {
                float s = ps[j];
                s += __shfl_xor(s, 1); s += __shfl_xor(s, 2);
                s += __shfl_xor(s, 4); s += __shfl_xor(s, 8);
                if (l15 == 0) atomicAdd(&rsum[m * 16 + lh * 4 + j], s);
            }
        }
        // ---- O += P . Vc^T (keys 128, via 2 ks-steps) ----
        #pragma unroll
        for (int ks = 0; ks < 128; ks += 64) {
            #pragma unroll
            for (int i = 0; i < 8; ++i) {
                const int c = i * 4 + w;               // d-rows 0..255
                const ushort_t* g = Vp + (size_t)(c * 8 + srow) * 2048 + ch * 128 + ks + scol;
                __builtin_amdgcn_global_load_lds((GVoid*)g, (LVoid*)(Stg + c * 512), 16, 0, 0);
            }
            __syncthreads();
            #pragma unroll
            for (int kk = 0; kk < 2; ++kk) {
                bf16x8 pa[4], vb[4];
                #pragma unroll
                for (int m = 0; m < 4; ++m) {
                    const int row = m * 16 + l15;
                    const int cb = (ks * 2 + kk * 64 + lh * 16) ^ ((row & 7) << 4);
                    pa[m] = *reinterpret_cast<const bf16x8*>(
                        reinterpret_cast<const char*>(Pb) + row * 256 + cb);
                }
                #pragma unroll
                for (int n = 0; n < 4; ++n) {
                    const int row = w * 64 + n * 16 + l15;
                    const int cb = ((kk * 64) + lh * 16) ^ ((row & 7) << 4);
                    vb[n] = *reinterpret_cast<const bf16x8*>(
                        reinterpret_cast<const char*>(Stg) + row * 128 + cb);
                }
                #pragma unroll
                for (int m = 0; m < 4; ++m)
                    #pragma unroll
                    for (int n = 0; n < 4; ++n)
                        oacc[m][n] = __builtin_amdgcn_mfma_f32_16x16x32_bf16(
                            pa[m], vb[n], oacc[m][n], 0, 0, 0);
            }
            __syncthreads();
        }
    }

    // ---- epilogue: O / rowsum -> ctx ----
    #pragma unroll
    for (int m = 0; m < 4; ++m) {
        float riv[4];
        #pragma unroll
        for (int j = 0; j < 4; ++j)
            riv[j] = 1.f / rsum[m * 16 + lh * 4 + j];
        #pragma unroll
        for (int n = 0; n < 4; ++n) {
            const int dcol = w * 64 + n * 16 + l15;
            #pragma unroll
            for (int j = 0; j < 4; ++j) {
                const int row = m * 16 + lh * 4 + j;
                const size_t off = (size_t)(z1 * 2048 + m0 + row) * 1024 + z2 * 256 + dcol;
                ctx[off] = f2bf(oacc[m][n][j] * riv[j]);
            }
        }
    }
}

// ---------- 128x128 MFMA GEMM + T1 XCD swizzle + split-K dual operand ----------
// EPI: 0=f32, 1=bf16, 2=sigmoid->f32, 3=split gate(bf16 sigmoid)/h1(bf16)
// SPLIT: k>=1024 reads A2/B2 (k-1024), strides lda2/ldb2
template<int EPI, int BIAS, int SPLIT>
__global__ __launch_bounds__(256, 2)
void gemm_bt(const ushort_t* __restrict__ A, const ushort_t* __restrict__ B,
             const ushort_t* __restrict__ A2, const ushort_t* __restrict__ B2,
             int lda2, int ldb2,
             const float* __restrict__ bias, void* __restrict__ Cv,
             void* __restrict__ Cv2, const float* __restrict__ bias2,
             int K, int lda, int ldb, int ldc,
             long long sA1, long long sA2s, long long sAz,
             long long sB1, long long sB2s, long long sBz,
             long long sC1, long long sC2s, long long sCz,
             int z2n, int zbase, float scale)
{
    __shared__ __align__(16) ushort_t As[8192];
    __shared__ __align__(16) ushort_t Bs[8192];
    const int zz = blockIdx.z;
    const int zg = zz + zbase;
    const int z1 = zg / z2n, z2 = zg - z1 * z2n;
    A += (size_t)(z1 * sA1 + z2 * sA2s + zz * sAz);
    B += (size_t)(z1 * sB1 + z2 * sB2s + zz * sBz);
    const size_t cOff = (size_t)(z1 * sC1 + z2 * sC2s + zz * sCz);

    const int nwg = gridDim.x * gridDim.y;
    const int wg  = blockIdx.y * gridDim.x + blockIdx.x;
    const int q8  = nwg >> 3, r8 = nwg & 7;
    const int xcd = wg & 7, lo = wg >> 3;
    const int wgid = (xcd < r8 ? xcd * (q8 + 1) : r8 * (q8 + 1) + (xcd - r8) * q8) + lo;
    const int m0 = (wgid / gridDim.x) * 128, n0 = (wgid % gridDim.x) * 128;

    const int tid = threadIdx.x;
    const int w = tid >> 6, l = tid & 63;
    const int wm = w >> 1, wn = w & 1;

    f32x4 acc[4][4] = {};
    const int srow = l >> 3;
    const int scol = ((l & 7) ^ srow) << 3;

    for (int k0 = 0; k0 < K; k0 += 64) {
        const ushort_t* Ab = A; const ushort_t* Bb = B;
        int la = lda, lb = ldb, kk0 = k0;
        if (SPLIT && k0 >= 1024) { Ab = A2; Bb = B2; la = lda2; lb = ldb2; kk0 = k0 - 1024; }
        #pragma unroll
        for (int i = 0; i < 4; ++i) {
            const int c = i * 4 + w;
            const int row = c * 8 + srow;
            const ushort_t* ga = Ab + (size_t)(m0 + row) * la + (kk0 + scol);
            const ushort_t* gb = Bb + (size_t)(n0 + row) * lb + (kk0 + scol);
            __builtin_amdgcn_global_load_lds((GVoid*)ga, (LVoid*)(As + c * 512), 16, 0, 0);
            __builtin_amdgcn_global_load_lds((GVoid*)gb, (LVoid*)(Bs + c * 512), 16, 0, 0);
        }
        __syncthreads();
        #pragma unroll
        for (int kk = 0; kk < 2; ++kk) {
            bf16x8 af[4], bfv[4];
            #pragma unroll
            for (int m = 0; m < 4; ++m) {
                const int row = wm * 64 + m * 16 + (l & 15);
                const int cb = ((kk * 64) + ((l >> 4) * 16)) ^ ((row & 7) << 4);
                af[m] = *reinterpret_cast<const bf16x8*>(
                    reinterpret_cast<const char*>(As) + row * 128 + cb);
            }
            #pragma unroll
            for (int n = 0; n < 4; ++n) {
                const int row = wn * 64 + n * 16 + (l & 15);
                const int cb = ((kk * 64) + ((l >> 4) * 16)) ^ ((row & 7) << 4);
                bfv[n] = *reinterpret_cast<const bf16x8*>(
                    reinterpret_cast<const char*>(Bs) + row * 128 + cb);
            }
            #pragma unroll
            for (int m = 0; m < 4; ++m)
                #pragma unroll
                for (int n = 0; n < 4; ++n)
                    acc[m][n] = __builtin_amdgcn_mfma_f32_16x16x32_bf16(
                        af[m], bfv[n], acc[m][n], 0, 0, 0);
        }
        __syncthreads();
    }

    #pragma unroll
    for (int m = 0; m < 4; ++m) {
        const int grow = m0 + wm * 64 + m * 16 + ((l >> 4) << 2);
        #pragma unroll
        for (int n = 0; n < 4; ++n) {
            const int gcol = n0 + wn * 64 + n * 16 + (l & 15);
            float bc = (BIAS == 1) ? bias[gcol] : 0.f;
            #pragma unroll
            for (int j = 0; j < 4; ++j) {
                if (EPI == 3) {
                    float v = acc[m][n][j];
                    if (gcol < 1024) {
                        v += bias[gcol];
                        v = 1.f / (1.f + __expf(-v));
                        ((ushort_t*)Cv)[(size_t)(grow + j) * ldc + gcol] = f2bf(v);
                    } else {
                        v += bias2[gcol - 1024];
                        ((ushort_t*)Cv2)[(size_t)(grow + j) * 2048 + (gcol - 1024)] = f2bf(v);
                    }
                } else {
                    float v = acc[m][n][j] * scale;
                    if (BIAS == 1) v += bc;
                    if (BIAS == 2) v += bias[grow + j];
                    if (EPI == 2) v = 1.f / (1.f + __expf(-v));
                    const size_t off = cOff + (size_t)(grow + j) * ldc + gcol;
                    if (EPI == 1) ((ushort_t*)Cv)[off] = f2bf(v);
                    else          ((float*)Cv)[off]    = v;
                }
            }
        }
    }
}

// ---------- host ----------
extern "C" void kernel_launch(void* const* d_in, const int* in_sizes, int n_in,
                              void* d_out, int out_size, void* d_ws, size_t ws_size,
                              hipStream_t stream) {
    const float* x          = (const float*)d_in[0];
    const float* mem_keys   = (const float*)d_in[1];
    const float* importance = (const float*)d_in[2];
    const float* recency    = (const float*)d_in[3];
    const float* access_cnt = (const float*)d_in[4];
    const float* Wq         = (const float*)d_in[5];
    const float* bq         = (const float*)d_in[6];
    const float* in_w       = (const float*)d_in[7];
    const float* in_b       = (const float*)d_in[8];
    const float* out_w      = (const float*)d_in[9];
    const float* out_b      = (const float*)d_in[10];
    const float* gate_w     = (const float*)d_in[11];
    const float* gate_b     = (const float*)d_in[12];
    const float* int_w1     = (const float*)d_in[13];
    const float* int_b1     = (const float*)d_in[14];
    const float* int_ln_g   = (const float*)d_in[15];
    const float* int_ln_b   = (const float*)d_in[16];
    const float* int_w2     = (const float*)d_in[17];
    const float* int_b2     = (const float*)d_in[18];
    const float* ln1_g      = (const float*)d_in[19];
    const float* ln1_b      = (const float*)d_in[20];
    const float* ln2_g      = (const float*)d_in[21];
    const float* ln2_b      = (const float*)d_in[22];
    const float* sel_params = (const float*)d_in[23];

    char* ws = (char*)d_ws;
    size_t off = 0;
    auto alloc = [&](size_t bytes) -> char* {
        char* p = ws + off;
        off = (off + bytes + 255) & ~(size_t)255;
        return p;
    };

    int*      idx      = (int*)alloc(TOPK * 4);
    float*    beff     = (float*)alloc(1024 * 4);
    float*    beff3    = (float*)alloc(3072 * 4);
    ushort_t* wqT_bf   = (ushort_t*)alloc((size_t)1048576 * 2);
    ushort_t* outwT_bf = (ushort_t*)alloc((size_t)1048576 * 2);
    ushort_t* weff_bf  = (ushort_t*)alloc((size_t)1048576 * 2);
    ushort_t* inw_bf   = (ushort_t*)alloc((size_t)3145728 * 2);
    ushort_t* gw3      = (ushort_t*)alloc((size_t)6291456 * 2);   // [gate_w;int_w1]
    ushort_t* wfold3   = (ushort_t*)alloc((size_t)3145728 * 2);   // 3072x1024
    ushort_t* intw2_bf = (ushort_t*)alloc((size_t)2097152 * 2);
    ushort_t* mem_n    = (ushort_t*)alloc((size_t)TOPK * HDIM * 2);
    ushort_t* Kbuf     = (ushort_t*)alloc((size_t)TOPK * HDIM * 2);
    ushort_t* Vt       = (ushort_t*)alloc((size_t)HDIM * TOPK * 2);
    ushort_t* xbf      = (ushort_t*)alloc((size_t)NROWS * HDIM * 2);   // 16 MB
    ushort_t* Qbuf     = (ushort_t*)alloc((size_t)NROWS * HDIM * 2);   // 16 MB
    ushort_t* h1       = (ushort_t*)alloc((size_t)NROWS * 2048 * 2);   // 32 MB
    ushort_t* ctx      = (ushort_t*)alloc((size_t)NROWS * HDIM * 2);   // 16 MB
    ushort_t* integ    = ctx;                            // ctx dead after fused gemm
    ushort_t* gatev    = (ushort_t*)alloc((size_t)NROWS * HDIM * 2);   // 16 MB

    cvt_t2<<<dim3(16,16,2), 256, 0, stream>>>(Wq, out_w, wqT_bf, outwT_bf);
    cvt_all<<<11264, 256, 0, stream>>>(in_w, gate_w, int_w1, int_w2,
                                       inw_bf, gw3, intw2_bf);
    cvt_bf16<<<8192, 256, 0, stream>>>(x, xbf);
    bias_folds<<<4096, 256, 0, stream>>>(in_w, bq, in_b, gate_w, int_w1,
                                         gate_b, int_b1, out_b, beff, beff3);

    // W_eff = wq . Wq  (via Wq^T as B)
    gemm_bt<1,0,0><<<dim3(8,8,1), 256, 0, stream>>>(inw_bf, wqT_bf,
        nullptr, nullptr, 0, 0, nullptr, weff_bf, nullptr, nullptr,
        1024, 1024, 1024, 1024, 0,0,0, 0,0,0, 0,0,0, 1, 0, 1.f);
    // wfold3 = gw3[:,1024:] @ out_w  (via out_w^T as B)
    gemm_bt<1,0,0><<<dim3(8,24,1), 256, 0, stream>>>(gw3 + 1024, outwT_bf,
        nullptr, nullptr, 0, 0, nullptr, wfold3, nullptr, nullptr,
        1024, 2048, 1024, 1024, 0,0,0, 0,0,0, 0,0,0, 1, 0, 1.f);

    topk_rank<<<MMEM/32, 256, 0, stream>>>(sel_params, importance, recency,
                                           access_cnt, idx);
    gather_ln<<<TOPK, 256, 0, stream>>>(mem_keys, idx, ln1_g, ln1_b, mem_n);

    // Q = x @ W_eff^T + beff
    gemm_bt<1,1,0><<<dim3(8,64,1), 256, 0, stream>>>(xbf, weff_bf,
        nullptr, nullptr, 0, 0, beff, Qbuf, nullptr, nullptr,
        1024, 1024, 1024, 1024, 0,0,0, 0,0,0, 0,0,0, 1, 0, 1.f);
    // K = mem_n @ wk^T + bki
    gemm_bt<1,1,0><<<dim3(8,16,1), 256, 0, stream>>>(mem_n, inw_bf + 1048576,
        nullptr, nullptr, 0, 0, in_b + 1024, Kbuf, nullptr, nullptr,
        1024, 1024, 1024, 1024, 0,0,0, 0,0,0, 0,0,0, 1, 0, 1.f);
    // Vt = wv @ mem_n^T + bvi(per-row)
    gemm_bt<1,2,0><<<dim3(16,8,1), 256, 0, stream>>>(inw_bf + 2097152, mem_n,
        nullptr, nullptr, 0, 0, in_b + 2048, Vt, nullptr, nullptr,
        1024, 1024, 1024, 2048, 0,0,0, 0,0,0, 0,0,0, 1, 0, 1.f);

    // fused flash attention: ctx = softmax(Q K^T / 16) V
    fattn<<<dim3(32,16), 256, 0, stream>>>(Qbuf, Kbuf, Vt, ctx);

    // fused: [gate | h1] = x@gw3_left^T + ctx@wfold3^T + beff3
    gemm_bt<3,0,1><<<dim3(24,64,1), 256, 0, stream>>>(xbf, gw3,
        ctx, wfold3, 1024, 1024, beff3, gatev, h1, beff3 + 1024,
        2048, 1024, 2048, 1024, 0,0,0, 0,0,0, 0,0,0, 1, 0, 1.f);

    ln_gelu<<<NROWS, 256, 0, stream>>>(h1, int_ln_g, int_ln_b);
    // integ = h1 @ int_w2^T + int_b2
    gemm_bt<1,1,0><<<dim3(8,64,1), 256, 0, stream>>>(h1, intw2_bf,
        nullptr, nullptr, 0, 0, int_b2, integ, nullptr, nullptr,
        2048, 2048, 2048, 1024, 0,0,0, 0,0,0, 0,0,0, 1, 0, 1.f);
    final_ln<<<NROWS, 256, 0, stream>>>(x, gatev, integ, ln2_g, ln2_b, (float*)d_out);
}

// Round 14
// 535.106 us; speedup vs baseline: 1.1885x; 1.1885x over previous
//
#include <hip/hip_runtime.h>

#define HDIM 1024
#define MMEM 8192
#define TOPK 2048
#define NROWS 8192
#define LNEPS 1e-5f

typedef unsigned short ushort_t;
typedef __bf16 bf16x8 __attribute__((ext_vector_type(8)));
typedef float f32x4 __attribute__((ext_vector_type(4)));
typedef __attribute__((address_space(1))) const void GVoid;
typedef __attribute__((address_space(3))) void LVoid;

// ---------- helpers ----------
__device__ __forceinline__ ushort_t f2bf(float f) {
    union { float f; unsigned u; } c; c.f = f;
    unsigned r = c.u + 0x7fffu + ((c.u >> 16) & 1u);
    return (ushort_t)(r >> 16);
}
__device__ __forceinline__ float bf2f(ushort_t u) {
    union { unsigned u; float f; } c; c.u = ((unsigned)u) << 16; return c.f;
}
__device__ __forceinline__ float blk_red(float v, int op, float* red) {
    #pragma unroll
    for (int o = 32; o; o >>= 1) {
        float u = __shfl_down(v, o);
        v = op ? fmaxf(v, u) : v + u;
    }
    if ((threadIdx.x & 63) == 0) red[threadIdx.x >> 6] = v;
    __syncthreads();
    float r = op ? fmaxf(fmaxf(red[0], red[1]), fmaxf(red[2], red[3]))
                 : (red[0] + red[1]) + (red[2] + red[3]);
    __syncthreads();
    return r;
}

// ---------- top-k with inlined selection-score computation ----------
__global__ __launch_bounds__(256) void topk_rank(const float* __restrict__ sp,
        const float* __restrict__ imp, const float* __restrict__ rec,
        const float* __restrict__ ac, int* __restrict__ idx) {
    __shared__ float s[MMEM];
    __shared__ int pc[256];
    __shared__ float red[4];
    float p0 = sp[0], p1 = sp[1], p2 = sp[2];
    float mx3 = fmaxf(p0, fmaxf(p1, p2));
    float e0 = __expf(p0 - mx3), e1 = __expf(p1 - mx3), e2 = __expf(p2 - mx3);
    float inv3 = 1.f / (e0 + e1 + e2);
    float w0 = e0 * inv3, w1 = e1 * inv3, w2 = e2 * inv3;
    float m = -1e30f;
    for (int i = threadIdx.x; i < MMEM; i += 256) m = fmaxf(m, ac[i]);
    m = blk_red(m, 1, red);
    float rinv = 1.f / m;
    for (int i = threadIdx.x; i < MMEM; i += 256)
        s[i] = w0 * imp[i] + w1 * rec[i] + w2 * (ac[i] * rinv);
    __syncthreads();
    const int li = threadIdx.x & 31;
    const int jc = threadIdx.x >> 5;
    const int i  = blockIdx.x * 32 + li;
    const float si = s[i];
    int cnt = 0;
    const float4* sv = reinterpret_cast<const float4*>(s) + jc * 256;
    #pragma unroll 4
    for (int t = 0; t < 256; ++t) {
        float4 v = sv[t];
        int j0 = jc * 1024 + t * 4;
        cnt += (v.x > si) || (v.x == si && (j0 + 0) < i);
        cnt += (v.y > si) || (v.y == si && (j0 + 1) < i);
        cnt += (v.z > si) || (v.z == si && (j0 + 2) < i);
        cnt += (v.w > si) || (v.w == si && (j0 + 3) < i);
    }
    pc[threadIdx.x] = cnt;
    __syncthreads();
    if (threadIdx.x < 32) {
        int r = 0;
        #pragma unroll
        for (int c = 0; c < 8; ++c) r += pc[c * 32 + threadIdx.x];
        if (r < TOPK) idx[r] = blockIdx.x * 32 + threadIdx.x;
    }
}

__global__ __launch_bounds__(256) void gather_ln(const float* __restrict__ mem_keys,
        const int* __restrict__ idx, const float* __restrict__ g,
        const float* __restrict__ b, ushort_t* __restrict__ out) {
    __shared__ float red[4];
    int src = idx[blockIdx.x] & (MMEM - 1);
    const float* x = mem_keys + (size_t)src * HDIM;
    float4 v = reinterpret_cast<const float4*>(x)[threadIdx.x];
    float s = v.x + v.y + v.z + v.w;
    float ss = v.x*v.x + v.y*v.y + v.z*v.z + v.w*v.w;
    s  = blk_red(s, 0, red);
    ss = blk_red(ss, 0, red);
    float mu = s * (1.f / HDIM);
    float var = ss * (1.f / HDIM) - mu * mu;
    float rstd = rsqrtf(var + LNEPS);
    int c = threadIdx.x * 4;
    ushort4 o;
    o.x = f2bf((v.x - mu) * rstd * g[c+0] + b[c+0]);
    o.y = f2bf((v.y - mu) * rstd * g[c+1] + b[c+1]);
    o.z = f2bf((v.z - mu) * rstd * g[c+2] + b[c+2]);
    o.w = f2bf((v.w - mu) * rstd * g[c+3] + b[c+3]);
    *reinterpret_cast<ushort4*>(out + (size_t)blockIdx.x * HDIM + c) = o;
}

// merged weight + activation conversion (f32 -> bf16), incl. x -> xbf
__global__ __launch_bounds__(256) void cvt_all(const float* __restrict__ in_w,
        const float* __restrict__ gate_w, const float* __restrict__ int_w1,
        const float* __restrict__ int_w2, const float* __restrict__ x,
        ushort_t* __restrict__ inw_bf, ushort_t* __restrict__ gw3,
        ushort_t* __restrict__ intw2_bf, ushort_t* __restrict__ xbf) {
    const int b = blockIdx.x;
    const float* src; ushort_t* dst; int rel;
    if      (b < 3072)  { src = in_w;   dst = inw_bf;        rel = b; }
    else if (b < 5120)  { src = gate_w; dst = gw3;           rel = b - 3072; }
    else if (b < 9216)  { src = int_w1; dst = gw3 + 2097152; rel = b - 5120; }
    else if (b < 11264) { src = int_w2; dst = intw2_bf;      rel = b - 9216; }
    else                { src = x;      dst = xbf;           rel = b - 11264; }
    size_t i = ((size_t)rel * 256 + threadIdx.x) * 4;
    float4 v = *reinterpret_cast<const float4*>(src + i);
    ushort4 o = { f2bf(v.x), f2bf(v.y), f2bf(v.z), f2bf(v.w) };
    *reinterpret_cast<ushort4*>(dst + i) = o;
}

// two 1024x1024 f32 -> bf16 TRANSPOSED (z selects pair)
__global__ __launch_bounds__(256) void cvt_t2(const float* __restrict__ a,
        const float* __restrict__ b, ushort_t* __restrict__ oa,
        ushort_t* __restrict__ ob) {
    __shared__ ushort_t t[64][65];
    const float* in = blockIdx.z ? b : a;
    ushort_t* out   = blockIdx.z ? ob : oa;
    const int bx = blockIdx.x * 64, by = blockIdx.y * 64;
    const int r = threadIdx.x >> 4, c4 = (threadIdx.x & 15) << 2;
    #pragma unroll
    for (int rr = 0; rr < 64; rr += 16) {
        float4 v = *reinterpret_cast<const float4*>(in + (size_t)(by + r + rr) * 1024 + bx + c4);
        t[r + rr][c4 + 0] = f2bf(v.x);
        t[r + rr][c4 + 1] = f2bf(v.y);
        t[r + rr][c4 + 2] = f2bf(v.z);
        t[r + rr][c4 + 3] = f2bf(v.w);
    }
    __syncthreads();
    #pragma unroll
    for (int rr = 0; rr < 64; rr += 16) {
        const int i = r + rr;
        ushort4 o = { t[c4 + 0][i], t[c4 + 1][i], t[c4 + 2][i], t[c4 + 3][i] };
        *reinterpret_cast<ushort4*>(out + (size_t)(bx + i) * 1024 + by + c4) = o;
    }
}

// merged bias folds
__global__ __launch_bounds__(256) void bias_folds(const float* __restrict__ in_w,
        const float* __restrict__ bq, const float* __restrict__ in_b,
        const float* __restrict__ gate_w, const float* __restrict__ int_w1,
        const float* __restrict__ gate_b, const float* __restrict__ int_b1,
        const float* __restrict__ out_b, float* __restrict__ beff,
        float* __restrict__ beff3) {
    __shared__ float red[4];
    const int b = blockIdx.x;
    const float* wrow; const float* vec;
    if (b < 1024) { wrow = in_w + (size_t)b * 1024; vec = bq; }
    else {
        const int j = b - 1024;
        wrow = (j < 1024 ? gate_w + (size_t)j * 2048
                         : int_w1 + (size_t)(j - 1024) * 2048) + 1024;
        vec = out_b;
    }
    const float4 wv = reinterpret_cast<const float4*>(wrow)[threadIdx.x];
    const float4 bv = reinterpret_cast<const float4*>(vec)[threadIdx.x];
    float s = wv.x*bv.x + wv.y*bv.y + wv.z*bv.z + wv.w*bv.w;
    s = blk_red(s, 0, red);
    if (threadIdx.x == 0) {
        if (b < 1024) beff[b] = s + in_b[b];
        else {
            const int j = b - 1024;
            beff3[j] = s + (j < 1024 ? gate_b[j] : int_b1[j - 1024]);
        }
    }
}

__global__ __launch_bounds__(256) void ln_gelu(ushort_t* h1,
        const float* __restrict__ g, const float* __restrict__ b) {
    __shared__ float red[4];
    ushort_t* p = h1 + (size_t)blockIdx.x * 2048 + threadIdx.x * 8;
    ushort4 a = reinterpret_cast<const ushort4*>(p)[0];
    ushort4 c = reinterpret_cast<const ushort4*>(p)[1];
    float v[8] = { bf2f(a.x), bf2f(a.y), bf2f(a.z), bf2f(a.w),
                   bf2f(c.x), bf2f(c.y), bf2f(c.z), bf2f(c.w) };
    float s = 0.f, ss = 0.f;
    #pragma unroll
    for (int j = 0; j < 8; ++j) { s += v[j]; ss += v[j]*v[j]; }
    s  = blk_red(s, 0, red);
    ss = blk_red(ss, 0, red);
    float mu = s * (1.f / 2048.f);
    float var = ss * (1.f / 2048.f) - mu * mu;
    float rstd = rsqrtf(var + LNEPS);
    int c0 = threadIdx.x * 8;
    ushort_t o[8];
    #pragma unroll
    for (int j = 0; j < 8; ++j) {
        float xn = (v[j] - mu) * rstd * g[c0 + j] + b[c0 + j];
        float ge = 0.5f * xn * (1.f + erff(xn * 0.70710678118654752f));
        o[j] = f2bf(ge);
    }
    ushort4 o1 = { o[0], o[1], o[2], o[3] };
    ushort4 o2 = { o[4], o[5], o[6], o[7] };
    reinterpret_cast<ushort4*>(p)[0] = o1;
    reinterpret_cast<ushort4*>(p)[1] = o2;
}

__global__ __launch_bounds__(256) void final_ln(const float* __restrict__ x,
        const ushort_t* __restrict__ gate, const ushort_t* __restrict__ integ,
        const float* __restrict__ g, const float* __restrict__ b,
        float* __restrict__ out) {
    __shared__ float red[4];
    size_t base = (size_t)blockIdx.x * HDIM + threadIdx.x * 4;
    float4 xv = *reinterpret_cast<const float4*>(x + base);
    ushort4 gv = *reinterpret_cast<const ushort4*>(gate + base);
    ushort4 iv = *reinterpret_cast<const ushort4*>(integ + base);
    float v[4] = { xv.x + bf2f(gv.x)*bf2f(iv.x), xv.y + bf2f(gv.y)*bf2f(iv.y),
                   xv.z + bf2f(gv.z)*bf2f(iv.z), xv.w + bf2f(gv.w)*bf2f(iv.w) };
    float s = v[0]+v[1]+v[2]+v[3];
    float ss = v[0]*v[0]+v[1]*v[1]+v[2]*v[2]+v[3]*v[3];
    s  = blk_red(s, 0, red);
    ss = blk_red(ss, 0, red);
    float mu = s * (1.f / HDIM);
    float var = ss * (1.f / HDIM) - mu * mu;
    float rstd = rsqrtf(var + LNEPS);
    int c = threadIdx.x * 4;
    float4 o;
    o.x = (v[0] - mu) * rstd * g[c+0] + b[c+0];
    o.y = (v[1] - mu) * rstd * g[c+1] + b[c+1];
    o.z = (v[2] - mu) * rstd * g[c+2] + b[c+2];
    o.w = (v[3] - mu) * rstd * g[c+3] + b[c+3];
    *reinterpret_cast<float4*>(out + base) = o;
}

// ---------- fused flash attention (round-10 shape + T5 setprio) ----------
// grid (32 row-blocks of 64, 16 z = b*4+h), 256 threads (4 waves).
// Per chunk of 128 keys: S=Q.Kc^T -> exp -> P in swizzled LDS + rowsum
// -> O += P.Vc. Final: O /= rowsum.
__global__ __launch_bounds__(256, 2)
void fattn(const ushort_t* __restrict__ Q, const ushort_t* __restrict__ Kb,
           const ushort_t* __restrict__ Vt, ushort_t* __restrict__ ctx)
{
    __shared__ __align__(16) ushort_t Pb[8192];      // 64 x 128 bf16 (swizzled)
    __shared__ __align__(16) ushort_t Stg[16384];    // Q(8K)+K(16K) | V(32K)
    __shared__ float rsum[64];

    const int z1 = blockIdx.y >> 2, z2 = blockIdx.y & 3;
    const int m0 = blockIdx.x * 64;
    const ushort_t* Qp = Q  + (size_t)z1 * 2097152 + z2 * 256;   // ld 1024
    const ushort_t* Kp = Kb + z2 * 256;                           // ld 1024
    const ushort_t* Vp = Vt + (size_t)z2 * 524288;                // ld 2048

    const int tid = threadIdx.x;
    const int w = tid >> 6, l = tid & 63;
    const int srow = l >> 3;
    const int scol = ((l & 7) ^ srow) << 3;
    const int l15 = l & 15, lh = l >> 4;

    if (tid < 64) rsum[tid] = 0.f;

    f32x4 oacc[4][4] = {};

    for (int ch = 0; ch < 16; ++ch) {
        f32x4 sacc[4][2] = {};
        // ---- S = Q . Kc^T (D = 256) ----
        for (int k0 = 0; k0 < 256; k0 += 64) {
            #pragma unroll
            for (int i = 0; i < 2; ++i) {
                const int c = i * 4 + w;
                const ushort_t* g = Qp + (size_t)(m0 + c * 8 + srow) * 1024 + k0 + scol;
                __builtin_amdgcn_global_load_lds((GVoid*)g, (LVoid*)(Stg + c * 512), 16, 0, 0);
            }
            #pragma unroll
            for (int i = 0; i < 4; ++i) {
                const int c = i * 4 + w;
                const ushort_t* g = Kp + (size_t)(ch * 128 + c * 8 + srow) * 1024 + k0 + scol;
                __builtin_amdgcn_global_load_lds((GVoid*)g, (LVoid*)(Stg + 4096 + c * 512), 16, 0, 0);
            }
            __syncthreads();
            #pragma unroll
            for (int kk = 0; kk < 2; ++kk) {
                bf16x8 af[4], bv[2];
                #pragma unroll
                for (int m = 0; m < 4; ++m) {
                    const int row = m * 16 + l15;
                    const int cb = ((kk * 64) + lh * 16) ^ ((row & 7) << 4);
                    af[m] = *reinterpret_cast<const bf16x8*>(
                        reinterpret_cast<const char*>(Stg) + row * 128 + cb);
                }
                #pragma unroll
                for (int n = 0; n < 2; ++n) {
                    const int row = w * 32 + n * 16 + l15;
                    const int cb = ((kk * 64) + lh * 16) ^ ((row & 7) << 4);
                    bv[n] = *reinterpret_cast<const bf16x8*>(
                        reinterpret_cast<const char*>(Stg) + 8192 + row * 128 + cb);
                }
                __builtin_amdgcn_s_setprio(1);
                #pragma unroll
                for (int m = 0; m < 4; ++m)
                    #pragma unroll
                    for (int n = 0; n < 2; ++n)
                        sacc[m][n] = __builtin_amdgcn_mfma_f32_16x16x32_bf16(
                            af[m], bv[n], sacc[m][n], 0, 0, 0);
                __builtin_amdgcn_s_setprio(0);
            }
            __syncthreads();
        }
        // ---- exp, P -> LDS (swizzled), rowsum ----
        #pragma unroll
        for (int m = 0; m < 4; ++m) {
            float ps[4] = {0.f, 0.f, 0.f, 0.f};
            #pragma unroll
            for (int n = 0; n < 2; ++n) {
                const int pcol = w * 32 + n * 16 + l15;
                #pragma unroll
                for (int j = 0; j < 4; ++j) {
                    const int prow = m * 16 + lh * 4 + j;
                    float e = __expf(sacc[m][n][j] * 0.0625f);
                    ps[j] += e;
                    const int cb = (pcol * 2) ^ ((prow & 7) << 4);
                    *reinterpret_cast<ushort_t*>(
                        reinterpret_cast<char*>(Pb) + prow * 256 + cb) = f2bf(e);
                }
            }
            #pragma unroll
            for (int j = 0; j < 4; ++j) {
                float s = ps[j];
                s += __shfl_xor(s, 1); s += __shfl_xor(s, 2);
                s += __shfl_xor(s, 4); s += __shfl_xor(s, 8);
                if (l15 == 0) atomicAdd(&rsum[m * 16 + lh * 4 + j], s);
            }
        }
        // ---- O += P . Vc^T (keys 128, via 2 ks-steps) ----
        #pragma unroll
        for (int ks = 0; ks < 128; ks += 64) {
            #pragma unroll
            for (int i = 0; i < 8; ++i) {
                const int c = i * 4 + w;
                const ushort_t* g = Vp + (size_t)(c * 8 + srow) * 2048 + ch * 128 + ks + scol;
                __builtin_amdgcn_global_load_lds((GVoid*)g, (LVoid*)(Stg + c * 512), 16, 0, 0);
            }
            __syncthreads();
            #pragma unroll
            for (int kk = 0; kk < 2; ++kk) {
                bf16x8 pa[4], vb[4];
                #pragma unroll
                for (int m = 0; m < 4; ++m) {
                    const int row = m * 16 + l15;
                    const int cb = (ks * 2 + kk * 64 + lh * 16) ^ ((row & 7) << 4);
                    pa[m] = *reinterpret_cast<const bf16x8*>(
                        reinterpret_cast<const char*>(Pb) + row * 256 + cb);
                }
                #pragma unroll
                for (int n = 0; n < 4; ++n) {
                    const int row = w * 64 + n * 16 + l15;
                    const int cb = ((kk * 64) + lh * 16) ^ ((row & 7) << 4);
                    vb[n] = *reinterpret_cast<const bf16x8*>(
                        reinterpret_cast<const char*>(Stg) + row * 128 + cb);
                }
                __builtin_amdgcn_s_setprio(1);
                #pragma unroll
                for (int m = 0; m < 4; ++m)
                    #pragma unroll
                    for (int n = 0; n < 4; ++n)
                        oacc[m][n] = __builtin_amdgcn_mfma_f32_16x16x32_bf16(
                            pa[m], vb[n], oacc[m][n], 0, 0, 0);
                __builtin_amdgcn_s_setprio(0);
            }
            __syncthreads();
        }
    }

    // ---- epilogue: O / rowsum -> ctx ----
    #pragma unroll
    for (int m = 0; m < 4; ++m) {
        float riv[4];
        #pragma unroll
        for (int j = 0; j < 4; ++j)
            riv[j] = 1.f / rsum[m * 16 + lh * 4 + j];
        #pragma unroll
        for (int n = 0; n < 4; ++n) {
            const int dcol = w * 64 + n * 16 + l15;
            #pragma unroll
            for (int j = 0; j < 4; ++j) {
                const int row = m * 16 + lh * 4 + j;
                const size_t off = (size_t)(z1 * 2048 + m0 + row) * 1024 + z2 * 256 + dcol;
                ctx[off] = f2bf(oacc[m][n][j] * riv[j]);
            }
        }
    }
}

// ---------- 128x128 MFMA GEMM + T1 XCD swizzle + split-K dual operand ----------
// EPI: 0=f32, 1=bf16, 2=sigmoid->f32, 3=split gate(bf16 sigmoid)/h1(bf16)
// SPLIT: k>=1024 reads A2/B2 (k-1024), strides lda2/ldb2
template<int EPI, int BIAS, int SPLIT>
__global__ __launch_bounds__(256, 2)
void gemm_bt(const ushort_t* __restrict__ A, const ushort_t* __restrict__ B,
             const ushort_t* __restrict__ A2, const ushort_t* __restrict__ B2,
             int lda2, int ldb2,
             const float* __restrict__ bias, void* __restrict__ Cv,
             void* __restrict__ Cv2, const float* __restrict__ bias2,
             int K, int lda, int ldb, int ldc,
             long long sA1, long long sA2s, long long sAz,
             long long sB1, long long sB2s, long long sBz,
             long long sC1, long long sC2s, long long sCz,
             int z2n, int zbase, float scale)
{
    __shared__ __align__(16) ushort_t As[8192];
    __shared__ __align__(16) ushort_t Bs[8192];
    const int zz = blockIdx.z;
    const int zg = zz + zbase;
    const int z1 = zg / z2n, z2 = zg - z1 * z2n;
    A += (size_t)(z1 * sA1 + z2 * sA2s + zz * sAz);
    B += (size_t)(z1 * sB1 + z2 * sB2s + zz * sBz);
    const size_t cOff = (size_t)(z1 * sC1 + z2 * sC2s + zz * sCz);

    const int nwg = gridDim.x * gridDim.y;
    const int wg  = blockIdx.y * gridDim.x + blockIdx.x;
    const int q8  = nwg >> 3, r8 = nwg & 7;
    const int xcd = wg & 7, lo = wg >> 3;
    const int wgid = (xcd < r8 ? xcd * (q8 + 1) : r8 * (q8 + 1) + (xcd - r8) * q8) + lo;
    const int m0 = (wgid / gridDim.x) * 128, n0 = (wgid % gridDim.x) * 128;

    const int tid = threadIdx.x;
    const int w = tid >> 6, l = tid & 63;
    const int wm = w >> 1, wn = w & 1;

    f32x4 acc[4][4] = {};
    const int srow = l >> 3;
    const int scol = ((l & 7) ^ srow) << 3;

    for (int k0 = 0; k0 < K; k0 += 64) {
        const ushort_t* Ab = A; const ushort_t* Bb = B;
        int la = lda, lb = ldb, kk0 = k0;
        if (SPLIT && k0 >= 1024) { Ab = A2; Bb = B2; la = lda2; lb = ldb2; kk0 = k0 - 1024; }
        #pragma unroll
        for (int i = 0; i < 4; ++i) {
            const int c = i * 4 + w;
            const int row = c * 8 + srow;
            const ushort_t* ga = Ab + (size_t)(m0 + row) * la + (kk0 + scol);
            const ushort_t* gb = Bb + (size_t)(n0 + row) * lb + (kk0 + scol);
            __builtin_amdgcn_global_load_lds((GVoid*)ga, (LVoid*)(As + c * 512), 16, 0, 0);
            __builtin_amdgcn_global_load_lds((GVoid*)gb, (LVoid*)(Bs + c * 512), 16, 0, 0);
        }
        __syncthreads();
        #pragma unroll
        for (int kk = 0; kk < 2; ++kk) {
            bf16x8 af[4], bfv[4];
            #pragma unroll
            for (int m = 0; m < 4; ++m) {
                const int row = wm * 64 + m * 16 + (l & 15);
                const int cb = ((kk * 64) + ((l >> 4) * 16)) ^ ((row & 7) << 4);
                af[m] = *reinterpret_cast<const bf16x8*>(
                    reinterpret_cast<const char*>(As) + row * 128 + cb);
            }
            #pragma unroll
            for (int n = 0; n < 4; ++n) {
                const int row = wn * 64 + n * 16 + (l & 15);
                const int cb = ((kk * 64) + ((l >> 4) * 16)) ^ ((row & 7) << 4);
                bfv[n] = *reinterpret_cast<const bf16x8*>(
                    reinterpret_cast<const char*>(Bs) + row * 128 + cb);
            }
            #pragma unroll
            for (int m = 0; m < 4; ++m)
                #pragma unroll
                for (int n = 0; n < 4; ++n)
                    acc[m][n] = __builtin_amdgcn_mfma_f32_16x16x32_bf16(
                        af[m], bfv[n], acc[m][n], 0, 0, 0);
        }
        __syncthreads();
    }

    #pragma unroll
    for (int m = 0; m < 4; ++m) {
        const int grow = m0 + wm * 64 + m * 16 + ((l >> 4) << 2);
        #pragma unroll
        for (int n = 0; n < 4; ++n) {
            const int gcol = n0 + wn * 64 + n * 16 + (l & 15);
            float bc = (BIAS == 1) ? bias[gcol] : 0.f;
            #pragma unroll
            for (int j = 0; j < 4; ++j) {
                if (EPI == 3) {
                    float v = acc[m][n][j];
                    if (gcol < 1024) {
                        v += bias[gcol];
                        v = 1.f / (1.f + __expf(-v));
                        ((ushort_t*)Cv)[(size_t)(grow + j) * ldc + gcol] = f2bf(v);
                    } else {
                        v += bias2[gcol - 1024];
                        ((ushort_t*)Cv2)[(size_t)(grow + j) * 2048 + (gcol - 1024)] = f2bf(v);
                    }
                } else {
                    float v = acc[m][n][j] * scale;
                    if (BIAS == 1) v += bc;
                    if (BIAS == 2) v += bias[grow + j];
                    if (EPI == 2) v = 1.f / (1.f + __expf(-v));
                    const size_t off = cOff + (size_t)(grow + j) * ldc + gcol;
                    if (EPI == 1) ((ushort_t*)Cv)[off] = f2bf(v);
                    else          ((float*)Cv)[off]    = v;
                }
            }
        }
    }
}

// ---------- host ----------
extern "C" void kernel_launch(void* const* d_in, const int* in_sizes, int n_in,
                              void* d_out, int out_size, void* d_ws, size_t ws_size,
                              hipStream_t stream) {
    const float* x          = (const float*)d_in[0];
    const float* mem_keys   = (const float*)d_in[1];
    const float* importance = (const float*)d_in[2];
    const float* recency    = (const float*)d_in[3];
    const float* access_cnt = (const float*)d_in[4];
    const float* Wq         = (const float*)d_in[5];
    const float* bq         = (const float*)d_in[6];
    const float* in_w       = (const float*)d_in[7];
    const float* in_b       = (const float*)d_in[8];
    const float* out_w      = (const float*)d_in[9];
    const float* out_b      = (const float*)d_in[10];
    const float* gate_w     = (const float*)d_in[11];
    const float* gate_b     = (const float*)d_in[12];
    const float* int_w1     = (const float*)d_in[13];
    const float* int_b1     = (const float*)d_in[14];
    const float* int_ln_g   = (const float*)d_in[15];
    const float* int_ln_b   = (const float*)d_in[16];
    const float* int_w2     = (const float*)d_in[17];
    const float* int_b2     = (const float*)d_in[18];
    const float* ln1_g      = (const float*)d_in[19];
    const float* ln1_b      = (const float*)d_in[20];
    const float* ln2_g      = (const float*)d_in[21];
    const float* ln2_b      = (const float*)d_in[22];
    const float* sel_params = (const float*)d_in[23];

    char* ws = (char*)d_ws;
    size_t off = 0;
    auto alloc = [&](size_t bytes) -> char* {
        char* p = ws + off;
        off = (off + bytes + 255) & ~(size_t)255;
        return p;
    };

    int*      idx      = (int*)alloc(TOPK * 4);
    float*    beff     = (float*)alloc(1024 * 4);
    float*    beff3    = (float*)alloc(3072 * 4);
    ushort_t* wqT_bf   = (ushort_t*)alloc((size_t)1048576 * 2);
    ushort_t* outwT_bf = (ushort_t*)alloc((size_t)1048576 * 2);
    ushort_t* weff_bf  = (ushort_t*)alloc((size_t)1048576 * 2);
    ushort_t* inw_bf   = (ushort_t*)alloc((size_t)3145728 * 2);
    ushort_t* gw3      = (ushort_t*)alloc((size_t)6291456 * 2);   // [gate_w;int_w1]
    ushort_t* wfold3   = (ushort_t*)alloc((size_t)3145728 * 2);   // 3072x1024
    ushort_t* intw2_bf = (ushort_t*)alloc((size_t)2097152 * 2);
    ushort_t* mem_n    = (ushort_t*)alloc((size_t)TOPK * HDIM * 2);
    ushort_t* Kbuf     = (ushort_t*)alloc((size_t)TOPK * HDIM * 2);
    ushort_t* Vt       = (ushort_t*)alloc((size_t)HDIM * TOPK * 2);
    ushort_t* xbf      = (ushort_t*)alloc((size_t)NROWS * HDIM * 2);   // 16 MB
    ushort_t* Qbuf     = (ushort_t*)alloc((size_t)NROWS * HDIM * 2);   // 16 MB
    ushort_t* h1       = (ushort_t*)alloc((size_t)NROWS * 2048 * 2);   // 32 MB
    ushort_t* ctx      = (ushort_t*)alloc((size_t)NROWS * HDIM * 2);   // 16 MB
    ushort_t* integ    = ctx;                            // ctx dead after fused gemm
    ushort_t* gatev    = (ushort_t*)alloc((size_t)NROWS * HDIM * 2);   // 16 MB

    cvt_t2<<<dim3(16,16,2), 256, 0, stream>>>(Wq, out_w, wqT_bf, outwT_bf);
    cvt_all<<<19456, 256, 0, stream>>>(in_w, gate_w, int_w1, int_w2, x,
                                       inw_bf, gw3, intw2_bf, xbf);
    bias_folds<<<4096, 256, 0, stream>>>(in_w, bq, in_b, gate_w, int_w1,
                                         gate_b, int_b1, out_b, beff, beff3);

    // W_eff = wq . Wq  (via Wq^T as B)
    gemm_bt<1,0,0><<<dim3(8,8,1), 256, 0, stream>>>(inw_bf, wqT_bf,
        nullptr, nullptr, 0, 0, nullptr, weff_bf, nullptr, nullptr,
        1024, 1024, 1024, 1024, 0,0,0, 0,0,0, 0,0,0, 1, 0, 1.f);
    // wfold3 = gw3[:,1024:] @ out_w  (via out_w^T as B)
    gemm_bt<1,0,0><<<dim3(8,24,1), 256, 0, stream>>>(gw3 + 1024, outwT_bf,
        nullptr, nullptr, 0, 0, nullptr, wfold3, nullptr, nullptr,
        1024, 2048, 1024, 1024, 0,0,0, 0,0,0, 0,0,0, 1, 0, 1.f);

    topk_rank<<<MMEM/32, 256, 0, stream>>>(sel_params, importance, recency,
                                           access_cnt, idx);
    gather_ln<<<TOPK, 256, 0, stream>>>(mem_keys, idx, ln1_g, ln1_b, mem_n);

    // Q = x @ W_eff^T + beff
    gemm_bt<1,1,0><<<dim3(8,64,1), 256, 0, stream>>>(xbf, weff_bf,
        nullptr, nullptr, 0, 0, beff, Qbuf, nullptr, nullptr,
        1024, 1024, 1024, 1024, 0,0,0, 0,0,0, 0,0,0, 1, 0, 1.f);
    // K = mem_n @ wk^T + bki
    gemm_bt<1,1,0><<<dim3(8,16,1), 256, 0, stream>>>(mem_n, inw_bf + 1048576,
        nullptr, nullptr, 0, 0, in_b + 1024, Kbuf, nullptr, nullptr,
        1024, 1024, 1024, 1024, 0,0,0, 0,0,0, 0,0,0, 1, 0, 1.f);
    // Vt = wv @ mem_n^T + bvi(per-row)
    gemm_bt<1,2,0><<<dim3(16,8,1), 256, 0, stream>>>(inw_bf + 2097152, mem_n,
        nullptr, nullptr, 0, 0, in_b + 2048, Vt, nullptr, nullptr,
        1024, 1024, 1024, 2048, 0,0,0, 0,0,0, 0,0,0, 1, 0, 1.f);

    // fused flash attention: ctx = softmax(Q K^T / 16) V
    fattn<<<dim3(32,16), 256, 0, stream>>>(Qbuf, Kbuf, Vt, ctx);

    // fused: [gate | h1] = x@gw3_left^T + ctx@wfold3^T + beff3
    gemm_bt<3,0,1><<<dim3(24,64,1), 256, 0, stream>>>(xbf, gw3,
        ctx, wfold3, 1024, 1024, beff3, gatev, h1, beff3 + 1024,
        2048, 1024, 2048, 1024, 0,0,0, 0,0,0, 0,0,0, 1, 0, 1.f);

    ln_gelu<<<NROWS, 256, 0, stream>>>(h1, int_ln_g, int_ln_b);
    // integ = h1 @ int_w2^T + int_b2
    gemm_bt<1,1,0><<<dim3(8,64,1), 256, 0, stream>>>(h1, intw2_bf,
        nullptr, nullptr, 0, 0, int_b2, integ, nullptr, nullptr,
        2048, 2048, 2048, 1024, 0,0,0, 0,0,0, 0,0,0, 1, 0, 1.f);
    final_ln<<<NROWS, 256, 0, stream>>>(x, gatev, integ, ln2_g, ln2_b, (float*)d_out);
}